// Round 3
// baseline (86.945 us; speedup 1.0000x reference)
//
#include <hip/hip_runtime.h>
#include <math.h>

// Proto_77687368450665: few-shot proto-distance + log_softmax
// WAY=5 SHOT=5 QSHOT=15, D=640, M=25, G=4, Q=5
#define NS 25        // WAY*SHOT (support count)
#define NQ 75        // WAY*QUERY_SHOT (query count)
#define DDIM 640
#define MDIM 25
#define MP 26        // padded LDS row stride (even -> b64-mergeable, 2-way bank alias = free)
#define NPAIR 1875   // NS*NQ
// logits = -l2_raw / (M*M) / (G*Q*Q*SHOT) = -l2_raw / (625*500) = -l2_raw/312500

__global__ __launch_bounds__(256) void l2_kernel(
    const float* __restrict__ fm, const float* __restrict__ w2,
    const float* __restrict__ scale, float* __restrict__ logits)
{
    // bijective chunked XCD swizzle (m204): consecutive wgid chunks per XCD.
    // q-major pair order => each XCD touches ~10 Q slices + 25 S slices ~ 2.2MB < 4MB L2
    int orig = blockIdx.x;
    const int qch = NPAIR / 8;   // 234
    const int r   = NPAIR % 8;   // 3
    int xcd  = orig & 7;
    int base = (xcd < r) ? xcd * (qch + 1) : r * (qch + 1) + (xcd - r) * qch;
    int wgid = base + (orig >> 3);
    int q = wgid / NS;
    int s = wgid % NS;

    __shared__ float Slds[256 * MP];
    __shared__ float Qlds[256 * MP];
    __shared__ float red[4];

    int tid = threadIdx.x;

    // weights -> registers (uniform address per block; compiler can scalar-load)
    float w[MDIM];
    const float* wp = w2 + (s * NQ + q) * MDIM;
    #pragma unroll
    for (int m = 0; m < MDIM; ++m) w[m] = wp[m];

    const float* Sg = fm + (size_t)s * (DDIM * MDIM);
    const float* Qg = fm + (size_t)(NS + q) * (DDIM * MDIM);

    float partial = 0.f;

    for (int base_d = 0; base_d < DDIM; base_d += 256) {
        int len  = min(256, DDIM - base_d);  // 256, 256, 128
        int n4   = (len * MDIM) / 4;         // 1600 or 800 float4s (alignment: base mult of 16B)
        const float4* S4 = (const float4*)(Sg + base_d * MDIM);
        const float4* Q4 = (const float4*)(Qg + base_d * MDIM);
        for (int i = tid; i < n4; i += 256) {
            float4 v = S4[i];
            float4 u = Q4[i];
            int idx = 4 * i;
            #pragma unroll
            for (int k = 0; k < 4; ++k) {
                int dd = (idx + k) / MDIM, mm = (idx + k) % MDIM;
                Slds[dd * MP + mm] = (&v.x)[k];
                Qlds[dd * MP + mm] = (&u.x)[k];
            }
        }
        __syncthreads();
        if (tid < len) {
            const float* Sr = Slds + tid * MP;
            const float* Qr = Qlds + tid * MP;
            float acc = 0.f;
            #pragma unroll
            for (int m = 0; m < MDIM; ++m)
                acc += (Sr[m] - Qr[m]) * w[m];
            partial += acc * acc;
        }
        __syncthreads();
    }

    // wave butterfly reduce (64 lanes), then cross-wave via LDS
    #pragma unroll
    for (int off = 32; off >= 1; off >>= 1)
        partial += __shfl_xor(partial, off, 64);
    if ((tid & 63) == 0) red[tid >> 6] = partial;
    __syncthreads();
    if (tid == 0) {
        float tot = red[0] + red[1] + red[2] + red[3];
        logits[q * NS + s] = -tot * (1.0f / 312500.0f) * scale[0];
    }
}

__global__ __launch_bounds__(64) void lsm_kernel(const float* __restrict__ logits,
                                                float* __restrict__ out)
{
    int q = blockIdx.x;
    int t = threadIdx.x;
    float x = (t < NS) ? logits[q * NS + t] : -INFINITY;
    float mx = x;
    #pragma unroll
    for (int off = 32; off >= 1; off >>= 1)
        mx = fmaxf(mx, __shfl_xor(mx, off, 64));
    float e = (t < NS) ? expf(x - mx) : 0.f;
    float sum = e;
    #pragma unroll
    for (int off = 32; off >= 1; off >>= 1)
        sum += __shfl_xor(sum, off, 64);
    if (t < NS) out[q * NS + t] = x - mx - logf(sum);
}

extern "C" void kernel_launch(void* const* d_in, const int* in_sizes, int n_in,
                              void* d_out, int out_size, void* d_ws, size_t ws_size,
                              hipStream_t stream) {
    const float* fm    = (const float*)d_in[0];
    const float* w2    = (const float*)d_in[1];
    const float* scale = (const float*)d_in[2];
    float* logits = (float*)d_ws;     // 1875 floats of scratch
    float* out    = (float*)d_out;    // (75, 25) f32

    l2_kernel<<<NPAIR, 256, 0, stream>>>(fm, w2, scale, logits);
    lsm_kernel<<<NQ, 64, 0, stream>>>(logits, out);
}

// Round 5
// 83.923 us; speedup vs baseline: 1.0360x; 1.0360x over previous
//
#include <hip/hip_runtime.h>
#include <math.h>

// Proto_77687368450665: few-shot proto-distance + log_softmax
// WAY=5 SHOT=5 QSHOT=15 -> NS=25 support, NQ=75 query; D=640, M=25
// logits[q][s] = -(1/312500) * scale * sum_d ( sum_m (S[s,d,m]-Q[q,d,m]) w[s,q,m] )^2
// then log_softmax over s.
#define NS 25
#define NQ 75
#define DDIM 640
#define MDIM 25
#define SLICE (DDIM*MDIM)        // 16000 floats per feature-map slice
#define CHUNK_D 64               // d's per block
#define CHUNK_F (CHUNK_D*MDIM)   // 1600 floats per slice-chunk (6400B, 16B-aligned)
#define ST 5                     // s tiles of 5
#define QT 15                    // q tiles of 5
#define DC 10                    // d chunks
#define NBLK (ST*QT*DC)          // 750

// tiled partial-L2 kernel: block = (st,qt,dc), 320 threads = 5 waves.
// wave si stages S[s0+si] and Q[q0+si] chunks (linear global_load_lds memcpy),
// then computes 5 pairs (si, qi=0..4) for its 64 d-lanes; atomicAdd partials.
__global__ __launch_bounds__(320) void l2_kernel(const float* __restrict__ fm,
                                                 const float* __restrict__ w2,
                                                 float* __restrict__ raw)
{
    __shared__ float Sl[5 * CHUNK_F];   // 32000B
    __shared__ float Ql[5 * CHUNK_F];   // 32000B  -> 64KB total, 2 blocks/CU

    // bijective chunked XCD swizzle (m204): 750 = 8*93 + 6; consecutive dc
    // (same 10-slice working set) land on the same XCD's L2.
    int b = blockIdx.x;
    const int q8 = NBLK / 8, r8 = NBLK % 8;
    int xcd = b & 7;
    int wg = ((xcd < r8) ? xcd * (q8 + 1) : r8 * (q8 + 1) + (xcd - r8) * q8) + (b >> 3);
    int dc = wg % DC;
    int pq = wg / DC;                 // 0..74
    int qt = pq % QT, st = pq / QT;
    int s0 = st * 5, q0 = qt * 5;

    int tid  = threadIdx.x;
    int si   = __builtin_amdgcn_readfirstlane(tid >> 6);  // wave id 0..4 (SGPR)
    int lane = tid & 63;                                  // d within chunk

    // ---- staging: each wave copies its S and Q slice-chunks, pure linear ----
    const float* sg = fm + (size_t)(s0 + si) * SLICE + dc * CHUNK_F;
    const float* qg = fm + (size_t)(NS + q0 + si) * SLICE + dc * CHUNK_F;
    float* sl = Sl + si * CHUNK_F;
    float* ql = Ql + si * CHUNK_F;
    #pragma unroll
    for (int i = 0; i < 6; ++i) {   // 6 x 1024B per slice
        __builtin_amdgcn_global_load_lds(
            (const __attribute__((address_space(1))) void*)(sg + i * 256 + lane * 4),
            (__attribute__((address_space(3))) void*)(sl + i * 256), 16, 0, 0);
        __builtin_amdgcn_global_load_lds(
            (const __attribute__((address_space(1))) void*)(qg + i * 256 + lane * 4),
            (__attribute__((address_space(3))) void*)(ql + i * 256), 16, 0, 0);
    }
    // tail 256B (64 floats) per slice, width-4
    __builtin_amdgcn_global_load_lds(
        (const __attribute__((address_space(1))) void*)(sg + 1536 + lane),
        (__attribute__((address_space(3))) void*)(sl + 1536), 4, 0, 0);
    __builtin_amdgcn_global_load_lds(
        (const __attribute__((address_space(1))) void*)(qg + 1536 + lane),
        (__attribute__((address_space(3))) void*)(ql + 1536), 4, 0, 0);

    __syncthreads();   // compiler drains vmcnt before barrier (m97 pattern)

    // ---- compute: S-row in regs (read once); stride-25 b32 reads = 2-way = free ----
    float srow[MDIM];
    const float* srp = Sl + si * CHUNK_F + lane * MDIM;
    #pragma unroll
    for (int m = 0; m < MDIM; ++m) srow[m] = srp[m];

    float acc[5];
    #pragma unroll
    for (int qi = 0; qi < 5; ++qi) {
        // wave-uniform weight row -> scalar s_load path
        const float* wp = w2 + ((size_t)(s0 + si) * NQ + (q0 + qi)) * MDIM;
        const float* qrp = Ql + qi * CHUNK_F + lane * MDIM;
        float a = 0.f;
        #pragma unroll
        for (int m = 0; m < MDIM; ++m)
            a = fmaf(srow[m] - qrp[m], wp[m], a);
        acc[qi] = a * a;
    }

    // reduce each pair's partial over the 64 d-lanes, one atomic per (wave,qi)
    #pragma unroll
    for (int qi = 0; qi < 5; ++qi) {
        float v = acc[qi];
        #pragma unroll
        for (int off = 32; off >= 1; off >>= 1)
            v += __shfl_xor(v, off, 64);
        if (lane == 0)
            atomicAdd(&raw[(q0 + qi) * NS + (s0 + si)], v);
    }
}

// log_softmax over 25 supports per query; folds -1/312500 * scale
__global__ __launch_bounds__(64) void lsm_kernel(const float* __restrict__ raw,
                                                 const float* __restrict__ scale,
                                                 float* __restrict__ out)
{
    int q = blockIdx.x;
    int t = threadIdx.x;
    float sc = scale[0] * (-1.0f / 312500.0f);
    float x = (t < NS) ? raw[q * NS + t] * sc : -INFINITY;
    float mx = x;
    #pragma unroll
    for (int off = 32; off >= 1; off >>= 1)
        mx = fmaxf(mx, __shfl_xor(mx, off, 64));
    float e = (t < NS) ? expf(x - mx) : 0.f;
    float sum = e;
    #pragma unroll
    for (int off = 32; off >= 1; off >>= 1)
        sum += __shfl_xor(sum, off, 64);
    if (t < NS) out[q * NS + t] = x - mx - logf(sum);
}

extern "C" void kernel_launch(void* const* d_in, const int* in_sizes, int n_in,
                              void* d_out, int out_size, void* d_ws, size_t ws_size,
                              hipStream_t stream) {
    const float* fm    = (const float*)d_in[0];
    const float* w2    = (const float*)d_in[1];
    const float* scale = (const float*)d_in[2];
    float* raw = (float*)d_ws;        // 1875 floats of scratch (atomic accumulators)
    float* out = (float*)d_out;       // (75, 25) f32

    hipMemsetAsync(raw, 0, NQ * NS * sizeof(float), stream);  // graph-capturable
    l2_kernel<<<NBLK, 320, 0, stream>>>(fm, w2, raw);
    lsm_kernel<<<NQ, 64, 0, stream>>>(raw, scale, out);
}

// Round 10
// 79.202 us; speedup vs baseline: 1.0978x; 1.0596x over previous
//
#include <hip/hip_runtime.h>
#include <math.h>

// Proto_77687368450665: few-shot proto-distance + log_softmax
// WAY=5 SHOT=5 QSHOT=15 -> NS=25 support, NQ=75 query; D=640, M=25
// logits[q][s] = -(1/312500) * scale * sum_d ( sum_m (S[s,d,m]-Q[q,d,m]) w[s,q,m] )^2
// then log_softmax over s.
#define NS 25
#define NQ 75
#define DDIM 640
#define MDIM 25
#define SLICE (DDIM*MDIM)        // 16000 floats per feature-map slice
#define CHUNK_D 64               // d's per block
#define CHUNK_F (CHUNK_D*MDIM)   // 1600 floats per slice-chunk (6400B, 16B-aligned)
#define ST 5                     // s tiles of 5
#define QT 15                    // q tiles of 5
#define DC 10                    // d chunks
#define NBLK (ST*QT*DC)          // 750
#define NPAIR (NS*NQ)            // 1875

// tiled partial-L2 kernel: block = (st,qt,dc), 320 threads = 5 waves.
// wave si stages S[s0+si] and Q[q0+si] chunks (linear global_load_lds memcpy),
// then computes 5 pairs (si, qi=0..4) for its 64 d-lanes.
// Partials go to PRIVATE slots part[dc][q][s] -- pure overwrite, no init, no atomics.
__global__ __launch_bounds__(320) void l2_kernel(const float* __restrict__ fm,
                                                 const float* __restrict__ w2,
                                                 float* __restrict__ part)
{
    __shared__ float Sl[5 * CHUNK_F];   // 32000B
    __shared__ float Ql[5 * CHUNK_F];   // 32000B  -> 64KB total, 2 blocks/CU

    // bijective chunked XCD swizzle (m204): 750 = 8*93 + 6; consecutive dc
    // (same 10-slice working set) land on the same XCD's L2.
    int b = blockIdx.x;
    const int q8 = NBLK / 8, r8 = NBLK % 8;
    int xcd = b & 7;
    int wg = ((xcd < r8) ? xcd * (q8 + 1) : r8 * (q8 + 1) + (xcd - r8) * q8) + (b >> 3);
    int dc = wg % DC;
    int pq = wg / DC;                 // 0..74
    int qt = pq % QT, st = pq / QT;
    int s0 = st * 5, q0 = qt * 5;

    int tid  = threadIdx.x;
    int si   = __builtin_amdgcn_readfirstlane(tid >> 6);  // wave id 0..4 (SGPR)
    int lane = tid & 63;                                  // d within chunk

    // ---- staging: each wave copies its S and Q slice-chunks, pure linear ----
    // (byte-identical to the absmax-0.0-validated round-5 kernel)
    const float* sg = fm + (size_t)(s0 + si) * SLICE + dc * CHUNK_F;
    const float* qg = fm + (size_t)(NS + q0 + si) * SLICE + dc * CHUNK_F;
    float* sl = Sl + si * CHUNK_F;
    float* ql = Ql + si * CHUNK_F;
    #pragma unroll
    for (int i = 0; i < 6; ++i) {   // 6 x 1024B per slice
        __builtin_amdgcn_global_load_lds(
            (const __attribute__((address_space(1))) void*)(sg + i * 256 + lane * 4),
            (__attribute__((address_space(3))) void*)(sl + i * 256), 16, 0, 0);
        __builtin_amdgcn_global_load_lds(
            (const __attribute__((address_space(1))) void*)(qg + i * 256 + lane * 4),
            (__attribute__((address_space(3))) void*)(ql + i * 256), 16, 0, 0);
    }
    // tail 256B (64 floats) per slice, width-4
    __builtin_amdgcn_global_load_lds(
        (const __attribute__((address_space(1))) void*)(sg + 1536 + lane),
        (__attribute__((address_space(3))) void*)(sl + 1536), 4, 0, 0);
    __builtin_amdgcn_global_load_lds(
        (const __attribute__((address_space(1))) void*)(qg + 1536 + lane),
        (__attribute__((address_space(3))) void*)(ql + 1536), 4, 0, 0);

    __syncthreads();   // compiler drains vmcnt before barrier (m97 pattern)

    // ---- compute: S-row in regs (read once); stride-25 b32 reads = 2-way = free ----
    float srow[MDIM];
    const float* srp = Sl + si * CHUNK_F + lane * MDIM;
    #pragma unroll
    for (int m = 0; m < MDIM; ++m) srow[m] = srp[m];

    float acc[5];
    #pragma unroll
    for (int qi = 0; qi < 5; ++qi) {
        // wave-uniform weight row -> scalar s_load path
        const float* wp = w2 + ((size_t)(s0 + si) * NQ + (q0 + qi)) * MDIM;
        const float* qrp = Ql + qi * CHUNK_F + lane * MDIM;
        float a = 0.f;
        #pragma unroll
        for (int m = 0; m < MDIM; ++m)
            a = fmaf(srow[m] - qrp[m], wp[m], a);
        acc[qi] = a * a;
    }

    // reduce each pair's partial over the 64 d-lanes; one plain store per (wave,qi)
    #pragma unroll
    for (int qi = 0; qi < 5; ++qi) {
        float v = acc[qi];
        #pragma unroll
        for (int off = 32; off >= 1; off >>= 1)
            v += __shfl_xor(v, off, 64);
        if (lane == 0)
            part[dc * NPAIR + (q0 + qi) * NS + (s0 + si)] = v;
    }
}

// sums the 10 d-chunk partials, then log_softmax over 25 supports per query;
// folds -1/312500 * scale. Fixed summation order -> bit-deterministic.
__global__ __launch_bounds__(64) void lsm_kernel(const float* __restrict__ part,
                                                 const float* __restrict__ scale,
                                                 float* __restrict__ out)
{
    int q = blockIdx.x;
    int t = threadIdx.x;
    float sc = scale[0] * (-1.0f / 312500.0f);
    float x = -INFINITY;
    if (t < NS) {
        float tot = 0.f;
        #pragma unroll
        for (int dc = 0; dc < DC; ++dc)
            tot += part[dc * NPAIR + q * NS + t];
        x = tot * sc;
    }
    float mx = x;
    #pragma unroll
    for (int off = 32; off >= 1; off >>= 1)
        mx = fmaxf(mx, __shfl_xor(mx, off, 64));
    float e = (t < NS) ? expf(x - mx) : 0.f;
    float sum = e;
    #pragma unroll
    for (int off = 32; off >= 1; off >>= 1)
        sum += __shfl_xor(sum, off, 64);
    if (t < NS) out[q * NS + t] = x - mx - logf(sum);
}

extern "C" void kernel_launch(void* const* d_in, const int* in_sizes, int n_in,
                              void* d_out, int out_size, void* d_ws, size_t ws_size,
                              hipStream_t stream) {
    const float* fm    = (const float*)d_in[0];
    const float* w2    = (const float*)d_in[1];
    const float* scale = (const float*)d_in[2];
    float* part = (float*)d_ws;       // DC*NPAIR = 18750 floats of scratch (private slots)
    float* out  = (float*)d_out;      // (75, 25) f32

    l2_kernel<<<NBLK, 320, 0, stream>>>(fm, w2, part);
    lsm_kernel<<<NQ, 64, 0, stream>>>(part, scale, out);
}